// Round 14
// baseline (596.599 us; speedup 1.0000x reference)
//
#include <hip/hip_runtime.h>
#include <hip/hip_bf16.h>

#define B_  8
#define L_  4096
#define D_  2048
#define H_  16
#define HD_ 128
#define MK_ 1024
#define VTP 1040   // Vt row pitch (k dim, 1025 used + pad)
#define NNS 24576  // non-selected rows total (8 * 3072)

typedef __attribute__((ext_vector_type(8))) short short8;
typedef __attribute__((ext_vector_type(4))) float f32x4;

__device__ inline unsigned short f2bf(float f) {
  unsigned int u = __float_as_uint(f);
  unsigned int r = (u + 0x7fffu + ((u >> 16) & 1u)) >> 16;   // RNE
  return (unsigned short)r;
}

__device__ __forceinline__ void gload_lds16(const void* g, void* l) {
  __builtin_amdgcn_global_load_lds(
      (const __attribute__((address_space(1))) void*)g,
      (__attribute__((address_space(3))) void*)l, 16, 0, 0);
}

// ---------------- prep1: mask-dtype detect + rowmap + nsrow (blocks 0..7) + weight conv
__global__ __launch_bounds__(256) void prep1_kernel(
    const void* __restrict__ maskv, int* __restrict__ rowmap, int* __restrict__ nsrow,
    const float* __restrict__ W0, const float* __restrict__ W1,
    const float* __restrict__ W2, const float* __restrict__ W3,
    unsigned short* __restrict__ Wb) {
  int bid = blockIdx.x;
  int tid = threadIdx.x;
  if (bid < 8) {
    __shared__ int cnt;
    __shared__ int cnts[256];
    const unsigned char* m8 = (const unsigned char*)maskv;
    if (tid == 0) cnt = 0;
    __syncthreads();
    int local = 0;
    for (int i = tid; i < B_ * L_; i += 256) local += (m8[i] != 0);
    atomicAdd(&cnt, local);
    __syncthreads();
    int cv = cnt;
    int t = 0;
    if (cv == B_ * MK_)      t = 0; // u8 bool
    else if (cv == 2 * MK_)  t = 1; // i32
    else if (cv == 4 * MK_)  t = 2; // f32
    int b = bid;
    unsigned char loc[16];
    int c = 0;
    for (int j = 0; j < 16; ++j) {
      int pos = tid * 16 + j;
      int mv;
      if (t == 1)      mv = ((const int*)maskv)[b * L_ + pos] != 0;
      else if (t == 2) mv = ((const float*)maskv)[b * L_ + pos] != 0.0f;
      else             mv = m8[b * L_ + pos] != 0;
      loc[j] = (unsigned char)mv; c += mv;
    }
    cnts[tid] = c;
    __syncthreads();
    for (int off = 1; off < 256; off <<= 1) {
      int v = (tid >= off) ? cnts[tid - off] : 0;
      __syncthreads();
      cnts[tid] += v;
      __syncthreads();
    }
    int rank = cnts[tid] - c;
    for (int j = 0; j < 16; ++j) {
      int pos = tid * 16 + j;
      if (loc[j]) {
        if (rank < MK_) rowmap[b * MK_ + rank] = b * L_ + pos;
        ++rank;
      } else {
        int ns = pos - rank;              // rank = #selected before pos
        if (ns < 3072) nsrow[b * 3072 + ns] = b * L_ + pos;
      }
    }
  } else {
    const size_t per = (size_t)D_ * D_;
    int cb = bid - 8;
    int slab = cb >> 11;
    const float* W = (slab == 0) ? W0 : (slab == 1) ? W1 : (slab == 2) ? W2 : W3;
    size_t i = ((size_t)(cb & 2047) * 256 + tid) * 8;
    float4 a = *(const float4*)(W + i);
    float4 b4 = *(const float4*)(W + i + 4);
    uint4 o;
    o.x = f2bf(a.x)  | ((unsigned)f2bf(a.y)  << 16);
    o.y = f2bf(a.z)  | ((unsigned)f2bf(a.w)  << 16);
    o.z = f2bf(b4.x) | ((unsigned)f2bf(b4.y) << 16);
    o.w = f2bf(b4.z) | ((unsigned)f2bf(b4.w) << 16);
    *(uint4*)(Wb + slab * per + i) = o;
  }
}

// ---------------- prep2: gather+convert sig (blocks 0..8191) + register K/V rows
__global__ __launch_bounds__(256) void prep2_kernel(
    const float* __restrict__ x, const int* __restrict__ rowmap,
    unsigned short* __restrict__ sig,
    const float* __restrict__ reg, const float* __restrict__ Wrk, const float* __restrict__ brk,
    const float* __restrict__ Wrv, const float* __restrict__ brv,
    unsigned short* __restrict__ Kb, unsigned short* __restrict__ Vt) {
  int bid = blockIdx.x;
  int tid = threadIdx.x;
  if (bid < 8192) {
    int row = bid;
    const float* src = x + (size_t)rowmap[row] * D_;
    unsigned short* dst = sig + (size_t)row * D_;
    float4 a = ((const float4*)src)[tid * 2];
    float4 b4 = ((const float4*)src)[tid * 2 + 1];
    uint4 o;
    o.x = f2bf(a.x)  | ((unsigned)f2bf(a.y)  << 16);
    o.y = f2bf(a.z)  | ((unsigned)f2bf(a.w)  << 16);
    o.z = f2bf(b4.x) | ((unsigned)f2bf(b4.y) << 16);
    o.w = f2bf(b4.z) | ((unsigned)f2bf(b4.w) << 16);
    *(uint4*)(dst + tid * 8) = o;
  } else {
    int gw = ((bid - 8192) * 256 + tid) >> 6;  // 4096 waves
    int lane = tid & 63;
    int mat = gw >> 11;
    int n = gw & 2047;
    const float* W = mat ? Wrv : Wrk;
    const float* wrow = W + (size_t)n * D_;
    float s[8] = {};
    for (int j = 0; j < 8; ++j) {
      int e = j * 256 + lane * 4;
      float4 wv = *(const float4*)(wrow + e);
#pragma unroll
      for (int b = 0; b < 8; ++b) {
        float4 rv = *(const float4*)(reg + (size_t)b * D_ + e);
        s[b] += wv.x * rv.x + wv.y * rv.y + wv.z * rv.z + wv.w * rv.w;
      }
    }
#pragma unroll
    for (int off = 32; off; off >>= 1)
#pragma unroll
      for (int b = 0; b < 8; ++b) s[b] += __shfl_down(s[b], off);
    if (lane == 0) {
      float bias = (mat ? brv : brk)[n];
#pragma unroll
      for (int b = 0; b < 8; ++b) {
        unsigned short v = f2bf(s[b] + bias);
        if (mat) {
          Vt[(((size_t)b * 16 + (n >> 7)) * 128 + (n & 127)) * VTP + 1024] = v;
        } else {
          Kb[((size_t)b * 1025 + 1024) * D_ + n] = v;
        }
      }
    }
  }
}

// --------------------------------------- 256x256 BK=64 4-phase pipelined GEMM
// (frozen — LDS-bandwidth-bound at ~47-49% MfmaUtil across 5 schedule variants)
template<int FUSED>
__global__ __launch_bounds__(512, 2) void gemm8_kernel(
    const unsigned short* __restrict__ A, const unsigned short* __restrict__ Bw,
    const float* __restrict__ b0v, const float* __restrict__ b1v, const float* __restrict__ b2v,
    void* __restrict__ O0, void* __restrict__ O1, void* __restrict__ O2,
    const int* __restrict__ rowmap, float qalpha, int nbt, int matfix) {
  __shared__ __align__(16) unsigned short lds[2][2][2][8192];  // [buf][mat][half][128x64]
  int tid = threadIdx.x, lane = tid & 63, w = tid >> 6;
  int g = lane >> 4, l15 = lane & 15;
  int wm = w >> 2, wn = w & 3;

  int bid = blockIdx.x;
  int xcd = bid & 7, j = bid >> 3;          // grid = 8 * (4 * nbt)
  int mb = xcd * 4 + j / nbt, nb = j % nbt;
  int m0 = mb * 256, n0 = nb * 256;

  f32x4 acc[2][4][4] = {};

  int c0 = tid, c1 = tid + 512;
  int r0 = c0 >> 3, s0 = (c0 & 7) ^ (r0 & 7);
  int r1 = c1 >> 3, s1 = (c1 & 7) ^ (r1 & 7);
  int dst0 = (w * 64) * 8;
  int dst1 = (w * 64 + 512) * 8;

#define STAGE(MAT, HH, BUF, kt) {                                                 \
    const unsigned short* sp_ = (MAT) ? Bw : A;                                   \
    int gb_ = (MAT) ? n0 : m0;                                                    \
    gload_lds16(sp_ + (size_t)(gb_ + (HH)*128 + r0) * D_ + (kt)*64 + s0*8,        \
                &lds[BUF][MAT][HH][dst0]);                                        \
    gload_lds16(sp_ + (size_t)(gb_ + (HH)*128 + r1) * D_ + (kt)*64 + s1*8,        \
                &lds[BUF][MAT][HH][dst1]);                                        \
  }

  short8 a_[4][2], bb0[2][2], bb1[2][2];
#define RD_A(HH, BUF) { _Pragma("unroll")                                         \
    for (int mf_ = 0; mf_ < 4; ++mf_) {                                           \
      int rr_ = wm * 64 + mf_ * 16 + l15;                                         \
      _Pragma("unroll")                                                           \
      for (int ks_ = 0; ks_ < 2; ++ks_)                                           \
        a_[mf_][ks_] = *(const short8*)(&lds[BUF][0][HH][rr_ * 64 + ((ks_*4+g)^(rr_&7))*8]); } }
#define RD_B(DST, HH, BUF) { _Pragma("unroll")                                    \
    for (int nf_ = 0; nf_ < 2; ++nf_) {                                           \
      int rr_ = wn * 32 + nf_ * 16 + l15;                                         \
      _Pragma("unroll")                                                           \
      for (int ks_ = 0; ks_ < 2; ++ks_)                                           \
        DST[nf_][ks_] = *(const short8*)(&lds[BUF][1][HH][rr_ * 64 + ((ks_*4+g)^(rr_&7))*8]); } }
#define MF8(HA, NB, BSRC) { _Pragma("unroll")                                     \
    for (int mf_ = 0; mf_ < 4; ++mf_)                                             \
      _Pragma("unroll")                                                           \
      for (int nf_ = 0; nf_ < 2; ++nf_)                                           \
        _Pragma("unroll")                                                         \
        for (int ks_ = 0; ks_ < 2; ++ks_)                                         \
          acc[HA][mf_][(NB)+nf_] = __builtin_amdgcn_mfma_f32_16x16x32_bf16(       \
              a_[mf_][ks_], BSRC[nf_][ks_], acc[HA][mf_][(NB)+nf_], 0, 0, 0); }

  STAGE(0, 0, 0, 0); STAGE(1, 0, 0, 0); STAGE(1, 1, 0, 0); STAGE(0, 1, 0, 0);

  for (int T = 0; T < 32; ++T) {
    int BUF = T & 1;
    bool more = (T + 1 < 32);
    // ---- P1: A0 x B0 ----
    asm volatile("s_waitcnt vmcnt(4)" ::: "memory");
    __builtin_amdgcn_s_barrier();
    RD_A(0, BUF); RD_B(bb0, 0, BUF);
    if (more) STAGE(0, 0, BUF ^ 1, T + 1);
    asm volatile("s_waitcnt lgkmcnt(0)" ::: "memory");
    __builtin_amdgcn_sched_barrier(0);
    __builtin_amdgcn_s_setprio(1); MF8(0, 0, bb0); __builtin_amdgcn_s_setprio(0);
    // ---- P2: A0 x B1 ----
    if (more) asm volatile("s_waitcnt vmcnt(4)" ::: "memory");
    else      asm volatile("s_waitcnt vmcnt(2)" ::: "memory");
    __builtin_amdgcn_s_barrier();
    RD_B(bb1, 1, BUF);
    if (more) STAGE(1, 0, BUF ^ 1, T + 1);
    asm volatile("s_waitcnt lgkmcnt(0)" ::: "memory");
    __builtin_amdgcn_sched_barrier(0);
    __builtin_amdgcn_s_setprio(1); MF8(0, 2, bb1); __builtin_amdgcn_s_setprio(0);
    // ---- P3: A1 x B0 ----
    if (more) asm volatile("s_waitcnt vmcnt(4)" ::: "memory");
    else      asm volatile("s_waitcnt vmcnt(0)" ::: "memory");
    __builtin_amdgcn_s_barrier();
    RD_A(1, BUF);
    if (more) STAGE(1, 1, BUF ^ 1, T + 1);
    asm volatile("s_waitcnt lgkmcnt(0)" ::: "memory");
    __builtin_amdgcn_sched_barrier(0);
    __builtin_amdgcn_s_setprio(1); MF8(1, 0, bb0); __builtin_amdgcn_s_setprio(0);
    // ---- P4: A1 x B1 ----
    __builtin_amdgcn_s_barrier();
    if (more) STAGE(0, 1, BUF ^ 1, T + 1);
    __builtin_amdgcn_s_setprio(1); MF8(1, 2, bb1); __builtin_amdgcn_s_setprio(0);
  }
#undef MF8
#undef RD_B
#undef RD_A
#undef STAGE

  int mat = 0;
  const float* bias = b0v;
  float alpha = 1.0f;
  int n0l = n0;
  if (FUSED) {
    mat = (matfix >= 0) ? matfix : (n0 >> 11);
    bias = (mat == 0) ? b0v : ((mat == 1) ? b1v : b2v);
    alpha = (mat == 0) ? qalpha : 1.0f;
    n0l = n0 & 2047;
  }

#pragma unroll
  for (int hA = 0; hA < 2; ++hA) {
#pragma unroll
    for (int mf = 0; mf < 4; ++mf) {
#pragma unroll
      for (int nf = 0; nf < 4; ++nf) {
        int nn = n0l + (nf >> 1) * 128 + wn * 32 + (nf & 1) * 16 + l15;
        float bvv = bias[nn];
        int m = m0 + hA * 128 + wm * 64 + mf * 16 + g * 4;
        if (FUSED) {
          if (mat == 2) {                      // V -> transposed Vt
            int bb = m >> 10, tok = m & 1023;
            size_t base = (((size_t)bb * 16 + (nn >> 7)) * 128 + (nn & 127)) * VTP + tok;
            uint2 u;
            u.x = f2bf(acc[hA][mf][nf][0] + bvv) | ((unsigned)f2bf(acc[hA][mf][nf][1] + bvv) << 16);
            u.y = f2bf(acc[hA][mf][nf][2] + bvv) | ((unsigned)f2bf(acc[hA][mf][nf][3] + bvv) << 16);
            *(uint2*)((unsigned short*)O2 + base) = u;
          } else {
            unsigned short* out = (mat == 0) ? (unsigned short*)O0 : (unsigned short*)O1;
#pragma unroll
            for (int r = 0; r < 4; ++r) {
              float v = (acc[hA][mf][nf][r] + bvv) * alpha;
              int mm = m + r;
              int row = (mat == 1) ? mm + (mm >> 10) : mm;
              out[(size_t)row * D_ + nn] = f2bf(v);
            }
          }
        } else {
#pragma unroll
          for (int r = 0; r < 4; ++r) {
            int row = rowmap[m + r];
            ((float*)O0)[(size_t)row * D_ + nn] = acc[hA][mf][nf][r] + bvv;
          }
        }
      }
    }
  }
}

// ----------------------------------------------------------- flash attention
// Copy rows (non-selected only) now PREFETCHED ONE TILE-STEP AHEAD: x is
// HBM-cold (~900 cyc); the old same-iter load had only ~400 cyc of lead and
// exposed ~500 cyc per tile-step at the mid wait. Ping-pong reg sets A/B.
// vmcnt ledger (in-order queue per iter t):
//   [cl(t)3 (issued t-1), K(t)2 (issued t-1), stores(t-1)3, V(t)2, cl(t+1)3]
//   head wait: retire cl(t)+K(t) -> vmcnt(8)   (t==0 or t==nt-1: 5)
//   mid  wait: retire stores+V, keep cl(t+1)+K(t+1) -> vmcnt(5) (last: 0)
__device__ __forceinline__ void stage_k(const unsigned short* Kbase, unsigned short* dst,
                                        int kv0, int w, int lane) {
#pragma unroll
  for (int i = 0; i < 2; ++i) {
    int ib = w * 2 + i;
    int row = ib * 4 + (lane >> 4);
    int sl = (lane & 15) ^ (row & 7);
    int krow = kv0 + row; if (krow > MK_) krow = MK_;
    gload_lds16(Kbase + (size_t)krow * D_ + sl * 8, dst + ib * 512);
  }
}
__device__ __forceinline__ void stage_v(const unsigned short* Vbase, unsigned short* dst,
                                        int kv0, int w, int lane) {
#pragma unroll
  for (int i = 0; i < 2; ++i) {
    int ib = w * 2 + i;
    int row = ib * 8 + (lane >> 3);
    int sl = (lane & 7) ^ (row & 7);
    gload_lds16(Vbase + (size_t)row * VTP + kv0 + sl * 8, dst + ib * 512);
  }
}

__global__ __launch_bounds__(512) void attn_kernel(
    const unsigned short* __restrict__ Qb, const unsigned short* __restrict__ Kb,
    const unsigned short* __restrict__ Vt, unsigned short* __restrict__ Ob,
    const float4* __restrict__ xsrc, float4* __restrict__ xdst,
    const int* __restrict__ nsrow) {
  int bx = blockIdx.x;
  int gq = bx >> 7;                // 0 = heaviest
  int qi = 7 - gq;
  int bh = bx & 127;
  int b = bh >> 4, h = bh & 15;
  int tid = threadIdx.x, lane = tid & 63, w = tid >> 6;
  int g = lane >> 4, l15 = lane & 15;
  int q0 = qi * 128;
  int nt = 2 * qi + 3;             // causal tiles + register tile

  __shared__ __align__(16) unsigned short Ks[64 * 128];   // 16 KB, single buffer
  __shared__ __align__(16) unsigned short Vts[128 * 64];  // 16 KB
  __shared__ __align__(16) unsigned short Ps[8][16][72];  // 18 KB
  __shared__ int lds_ns[64];                               // copy-row list slice

  const unsigned short* Kbase = Kb + (size_t)b * 1025 * D_ + h * HD_;
  const unsigned short* Vbase = Vt + (size_t)bh * 128 * VTP;

  short8 qf[4];
  {
    const unsigned short* qrow = Qb + (size_t)(b * MK_ + q0 + w * 16 + l15) * D_ + h * HD_;
#pragma unroll
    for (int kk = 0; kk < 4; ++kk) qf[kk] = *(const short8*)(qrow + kk * 32 + g * 8);
  }

  f32x4 oacc[8] = {};
  float mrow[4], lrow[4];
#pragma unroll
  for (int r = 0; r < 4; ++r) { mrow[r] = -__builtin_inff(); lrow[r] = 0.f; }

  int qminw = q0 + w * 16;

  // preload this block's non-selected row list slice (nrows = 3*nt <= 51)
  {
    int nrows = nt * 3;
    int listBase = 384 * (18 * gq - gq * gq) + (bx & 127) * nrows;
    if (tid < nrows) {
      int li = listBase + tid; if (li > NNS - 1) li = NNS - 1;
      lds_ns[tid] = nsrow[li];
    }
  }
  // drain everything so the vmcnt ledger starts clean; lds_ns visible
  asm volatile("s_waitcnt vmcnt(0) lgkmcnt(0)" ::: "memory");
  __builtin_amdgcn_s_barrier();

  // copy ping-pong register sets: A = even chunks, B = odd chunks
  size_t ciA[3], ciB[3];
  float4 cvA[3], cvB[3];
#define CLOAD(CI, CV, c) {                                              \
    _Pragma("unroll")                                                   \
    for (int jj = 0; jj < 3; ++jj) {                                    \
      CI[jj] = (size_t)lds_ns[(c) * 3 + jj] * 512 + tid;                \
      CV[jj] = xsrc[CI[jj]];                                            \
    }                                                                   \
  }
#define CSTORE(CI, CV) {                                                \
    _Pragma("unroll")                                                   \
    for (int jj = 0; jj < 3; ++jj) xdst[CI[jj]] = CV[jj];               \
  }

  CLOAD(ciA, cvA, 0);               // prologue: chunk 0 loads (3)
  stage_k(Kbase, Ks, 0, w, lane);   // prologue: K(0) (2)

  for (int t = 0; t < nt; ++t) {
    int kv0 = (t < nt - 1) ? t * 64 : MK_;

    stage_v(Vbase, Vts, kv0, w, lane);             // (a) V(t) (2)
    if (t + 1 < nt) {                              // (b) prefetch chunk t+1 (3)
      if ((t + 1) & 1) CLOAD(ciB, cvB, t + 1)
      else             CLOAD(ciA, cvA, t + 1)
    }
    // (c) head wait: retire cl(t)+K(t) only
    if (t == 0 || t == nt - 1) asm volatile("s_waitcnt vmcnt(5)" ::: "memory");
    else                       asm volatile("s_waitcnt vmcnt(8)" ::: "memory");
    __builtin_amdgcn_s_barrier();    // barrier 1: Ks(t) visible

    bool active = (t == nt - 1) || (t * 64 <= qminw + 15);
    f32x4 sacc[4] = {};
    if (active) {
      __builtin_amdgcn_s_setprio(1);
#pragma unroll
      for (int kk = 0; kk < 4; ++kk) {
#pragma unroll
        for (int nf = 0; nf < 4; ++nf) {
          int krow = nf * 16 + l15;
          int sw = (kk * 4 + g) ^ (krow & 7);
          short8 kf = *(const short8*)(Ks + krow * 128 + sw * 8);
          sacc[nf] = __builtin_amdgcn_mfma_f32_16x16x32_bf16(qf[kk], kf, sacc[nf], 0, 0, 0);
        }
      }
      __builtin_amdgcn_s_setprio(0);
    }

    __builtin_amdgcn_s_barrier();    // barrier 1.5: all Ks reads in registers
    if (t + 1 < nt) {                // (d) K(t+1) prefetch under softmax/PV
      int kv1 = (t + 1 < nt - 1) ? (t + 1) * 64 : MK_;
      stage_k(Kbase, Ks, kv1, w, lane);
    }

    if (active) {
      if (t == nt - 1) {
#pragma unroll
        for (int nf = 0; nf < 4; ++nf) {
          int col = nf * 16 + l15;
          if (col != 0) {
#pragma unroll
            for (int r = 0; r < 4; ++r) sacc[nf][r] = -1e9f;
          }
        }
      } else if (t * 64 + 63 > qminw) {
        int qb = qminw - t * 64 + g * 4;
#pragma unroll
        for (int nf = 0; nf < 4; ++nf) {
          int col = nf * 16 + l15;
#pragma unroll
          for (int r = 0; r < 4; ++r)
            if (col > qb + r) sacc[nf][r] = -1e9f;
        }
      }

      float pm[4]; bool need = false;
#pragma unroll
      for (int r = 0; r < 4; ++r) {
        float mx = fmaxf(fmaxf(sacc[0][r], sacc[1][r]), fmaxf(sacc[2][r], sacc[3][r]));
        mx = fmaxf(mx, __shfl_xor(mx, 1));
        mx = fmaxf(mx, __shfl_xor(mx, 2));
        mx = fmaxf(mx, __shfl_xor(mx, 4));
        mx = fmaxf(mx, __shfl_xor(mx, 8));
        pm[r] = mx;
        need |= (mx > mrow[r] + 8.0f);
      }
      if (__any((int)need)) {
#pragma unroll
        for (int r = 0; r < 4; ++r) {
          float mnew = fmaxf(mrow[r], pm[r]);
          float sf = exp2f(mrow[r] - mnew);
          mrow[r] = mnew;
          lrow[r] *= sf;
#pragma unroll
          for (int i = 0; i < 8; ++i) oacc[i][r] *= sf;
        }
      }
      float rs[4] = {0.f, 0.f, 0.f, 0.f};
#pragma unroll
      for (int nf = 0; nf < 4; ++nf) {
#pragma unroll
        for (int r = 0; r < 4; ++r) {
          float p = exp2f(sacc[nf][r] - mrow[r]);
          sacc[nf][r] = p;
          rs[r] += p;
        }
      }
#pragma unroll
      for (int r = 0; r < 4; ++r) {
        float s = rs[r];
        s += __shfl_xor(s, 1);
        s += __shfl_xor(s, 2);
        s += __shfl_xor(s, 4);
        s += __shfl_xor(s, 8);
        lrow[r] += s;
      }
#pragma unroll
      for (int nf = 0; nf < 4; ++nf)
#pragma unroll
        for (int r = 0; r < 4; ++r)
          Ps[w][g * 4 + r][nf * 16 + l15] = f2bf(sacc[nf][r]);
    }

    // (e) mid wait: retire stores(t-1)+V(t); keep cl(t+1)+K(t+1) in flight
    if (t + 1 < nt) asm volatile("s_waitcnt vmcnt(5)" ::: "memory");
    else            asm volatile("s_waitcnt vmcnt(0)" ::: "memory");

    // (f) copy stores for chunk t (loaded one iter ago; retired at head wait)
    if (t & 1) CSTORE(ciB, cvB)
    else       CSTORE(ciA, cvA)

    __builtin_amdgcn_s_barrier();    // barrier 2: Vts ready

    if (active) {
      __builtin_amdgcn_s_setprio(1);
#pragma unroll
      for (int kk = 0; kk < 2; ++kk) {
        short8 pf = *(const short8*)(&Ps[w][l15][kk * 32 + g * 8]);
#pragma unroll
        for (int nf = 0; nf < 8; ++nf) {
          int vrow = nf * 16 + l15;
          int sw = (kk * 4 + g) ^ (vrow & 7);
          short8 vf = *(const short8*)(Vts + vrow * 64 + sw * 8);
          oacc[nf] = __builtin_amdgcn_mfma_f32_16x16x32_bf16(pf, vf, oacc[nf], 0, 0, 0);
        }
      }
      __builtin_amdgcn_s_setprio(0);
    }
    __builtin_amdgcn_s_barrier();    // barrier 3: protect Vts/Ps overwrite
  }
#undef CLOAD
#undef CSTORE

#pragma unroll
  for (int nf = 0; nf < 8; ++nf) {
#pragma unroll
    for (int r = 0; r < 4; ++r) {
      size_t row = (size_t)b * MK_ + q0 + w * 16 + g * 4 + r;
      Ob[row * D_ + h * HD_ + nf * 16 + l15] = f2bf(oacc[nf][r] / lrow[r]);
    }
  }
}

// ------------------------------------------------------------------- launch
extern "C" void kernel_launch(void* const* d_in, const int* in_sizes, int n_in,
                              void* d_out, int out_size, void* d_ws, size_t ws_size,
                              hipStream_t stream) {
  const float* x    = (const float*)d_in[0];
  const void*  mask = d_in[1];
  const float* reg  = (const float*)d_in[2];
  const float* Wq   = (const float*)d_in[3];
  const float* bq   = (const float*)d_in[4];
  const float* Wk   = (const float*)d_in[5];
  const float* bk   = (const float*)d_in[6];
  const float* Wv   = (const float*)d_in[7];
  const float* bv   = (const float*)d_in[8];
  const float* Wrk  = (const float*)d_in[9];
  const float* brk  = (const float*)d_in[10];
  const float* Wrv  = (const float*)d_in[11];
  const float* brv  = (const float*)d_in[12];
  const float* Wo   = (const float*)d_in[13];
  const float* bo   = (const float*)d_in[14];

  char* ws = (char*)d_ws;
  int* rowmap = (int*)(ws + 256);      // 32 KB  (ends 33024)
  int* nsrow  = (int*)(ws + 33024);    // 96 KB  (ends 131328)
  char* p = ws + 131328;
  unsigned short* sig = (unsigned short*)p;              p += (size_t)8192 * 2048 * 2;
  unsigned short* Qb  = (unsigned short*)p;              p += (size_t)8192 * 2048 * 2;
  unsigned short* Kb  = (unsigned short*)p;              p += (size_t)8200 * 2048 * 2;
  unsigned short* Vtb = (unsigned short*)p;              p += ((size_t)16384 * VTP + 64) * 2;
  unsigned short* Wbf = (unsigned short*)p;              // 33.6 MB fused / 8.4 MB fallback
  unsigned short* Ob  = sig;  // sig dead after QKV GEMM

  const size_t need_fused = (size_t)(p - ws) + (size_t)8192 * 2048 * 2;
  const bool fused = (ws_size >= need_fused);

  const float qalpha = 0.08838834764831845f * 1.4426950408889634f;
  const size_t per = (size_t)2048 * 2048;

  if (fused) {
    prep1_kernel<<<8200, 256, 0, stream>>>(mask, rowmap, nsrow, Wq, Wk, Wv, Wo, Wbf);
    prep2_kernel<<<9216, 256, 0, stream>>>(x, rowmap, sig, reg, Wrk, brk, Wrv, brv, Kb, Vtb);
    gemm8_kernel<1><<<768, 512, 0, stream>>>(sig, Wbf, bq, bk, bv, Qb, Kb, Vtb,
                                             nullptr, qalpha, 24, -1);
    attn_kernel<<<1024, 512, 0, stream>>>(Qb, Kb, Vtb, Ob, (const float4*)x, (float4*)d_out, nsrow);
    gemm8_kernel<0><<<256, 512, 0, stream>>>(Ob, Wbf + 3 * per, bo, nullptr, nullptr,
                                             d_out, nullptr, nullptr, rowmap, 1.0f, 8, -1);
  } else {
    prep1_kernel<<<8, 256, 0, stream>>>(mask, rowmap, nsrow, Wq, Wk, Wv, Wo, Wbf);
    prep2_kernel<<<9216, 256, 0, stream>>>(x, rowmap, sig, reg, Wrk, brk, Wrv, brv, Kb, Vtb);
    prep1_kernel<<<8200, 256, 0, stream>>>(mask, rowmap, nsrow, Wq, Wq, Wq, Wq, Wbf);
    gemm8_kernel<1><<<256, 512, 0, stream>>>(sig, Wbf, bq, bk, bv, Qb, Kb, Vtb,
                                             nullptr, qalpha, 8, 0);
    prep1_kernel<<<8200, 256, 0, stream>>>(mask, rowmap, nsrow, Wk, Wk, Wk, Wk, Wbf);
    gemm8_kernel<1><<<256, 512, 0, stream>>>(sig, Wbf, bq, bk, bv, Qb, Kb, Vtb,
                                             nullptr, qalpha, 8, 1);
    prep1_kernel<<<8200, 256, 0, stream>>>(mask, rowmap, nsrow, Wv, Wv, Wv, Wv, Wbf);
    gemm8_kernel<1><<<256, 512, 0, stream>>>(sig, Wbf, bq, bk, bv, Qb, Kb, Vtb,
                                             nullptr, qalpha, 8, 2);
    attn_kernel<<<1024, 512, 0, stream>>>(Qb, Kb, Vtb, Ob, (const float4*)x, (float4*)d_out, nsrow);
    prep1_kernel<<<8200, 256, 0, stream>>>(mask, rowmap, nsrow, Wo, Wo, Wo, Wo, Wbf);
    gemm8_kernel<0><<<256, 512, 0, stream>>>(Ob, Wbf, bo, nullptr, nullptr,
                                             d_out, nullptr, nullptr, rowmap, 1.0f, 8, -1);
  }
}